// Round 12
// baseline (655.874 us; speedup 1.0000x reference)
//
#include <hip/hip_runtime.h>

typedef __bf16 bf16x8 __attribute__((ext_vector_type(8)));
typedef float f32x4 __attribute__((ext_vector_type(4)));
typedef unsigned short u16x8 __attribute__((ext_vector_type(8)));

#define GLOAD16(gp, lp) __builtin_amdgcn_global_load_lds( \
    (const __attribute__((address_space(1))) void*)(gp), \
    (__attribute__((address_space(3))) void*)(lp), 16, 0, 0)

__device__ __forceinline__ unsigned short f2bf(float f) {
  union { float f; unsigned u; } c; c.f = f;
  unsigned u = c.u;
  u = (u + 0x7fffu + ((u >> 16) & 1u)) >> 16;
  return (unsigned short)u;
}
__device__ __forceinline__ float b2f(unsigned short u) {
  union { unsigned u; float f; } c; c.u = ((unsigned)u) << 16; return c.f;
}

// ---------- graph prep ----------
__global__ void k_count(const int* __restrict__ src_g, const int* __restrict__ dst_g,
                        const int* __restrict__ dst_s,
                        int* deg_og, int* deg_ig, int* cnt_s, int E)
{
  int e = blockIdx.x * blockDim.x + threadIdx.x;
  if (e >= E) return;
  atomicAdd(&deg_og[src_g[e]], 1);
  atomicAdd(&deg_ig[dst_g[e]], 1);
  atomicAdd(&cnt_s[dst_s[e]], 1);
}

// dual scan (blocks 0,1) + degree norms (blocks >= 2)
__global__ __launch_bounds__(1024) void k_scan(const int* __restrict__ deg0, int* __restrict__ offs0,
                                               const int* __restrict__ deg1, int* __restrict__ offs1,
                                               const int* __restrict__ deg_og, const int* __restrict__ deg_ig,
                                               float* __restrict__ ns, float* __restrict__ nd, int N)
{
  if (blockIdx.x >= 2) {
    int i = (blockIdx.x - 2) * 1024 + threadIdx.x;
    if (i < N) {
      int a = deg_og[i]; ns[i] = a > 0 ? rsqrtf((float)a) : 0.f;
      int b = deg_ig[i]; nd[i] = b > 0 ? rsqrtf((float)b) : 0.f;
    }
    return;
  }
  const int* deg = blockIdx.x ? deg1 : deg0;
  int* offs = blockIdx.x ? offs1 : offs0;
  __shared__ int part[1024];
  const int t = threadIdx.x;
  const int CH = (N + 1023) / 1024;
  const int b = t * CH;
  int s = 0;
  for (int i = 0; i < CH; ++i) {
    int idx = b + i;
    s += (idx < N) ? deg[idx] : 0;
  }
  part[t] = s;
  __syncthreads();
  for (int o = 1; o < 1024; o <<= 1) {
    int v = (t >= o) ? part[t - o] : 0;
    __syncthreads();
    part[t] += v;
    __syncthreads();
  }
  int run = (t == 0) ? 0 : part[t - 1];
  if (t == 0) offs[0] = 0;
  for (int i = 0; i < CH; ++i) {
    int idx = b + i;
    if (idx < N) { run += deg[idx]; offs[idx + 1] = run; }
  }
}

// dual fill: blockIdx.y==0 -> graph edges; ==1 -> score edges
__global__ void k_fill(const int* __restrict__ srcA, const int* __restrict__ dstA,
                       const int* __restrict__ offsA, int* curA, int* __restrict__ outA,
                       const int* __restrict__ srcB, const int* __restrict__ dstB,
                       const int* __restrict__ offsB, int* curB, int* __restrict__ outB, int E)
{
  int e = blockIdx.x * blockDim.x + threadIdx.x;
  if (e >= E) return;
  if (blockIdx.y == 0) {
    int d = dstA[e];
    int p = atomicAdd(&curA[d], 1);
    outA[offsA[d] + p] = srcA[e];
  } else {
    int d = dstB[e];
    int p = atomicAdd(&curB[d], 1);
    outB[offsB[d] + p] = srcB[e];
  }
}

// ---------- one-shot prep: feat cast + all weight transposes/concats + bias concats ----------
struct PrepArgs {
  const float *feat, *W1a, *W1at, *W1b, *W1bt, *W2, *W2t, *Wp;
  const float *b1a, *b1at, *b1b, *b1bt, *b2, *b2t;
  unsigned short *featb, *wcatL1, *wcat2, *wcatLin, *wtp;
  float *bcatL1, *bcatGcn, *bcatLin;
  int NF;
};
__global__ void k_prep(PrepArgs p)
{
  int i = blockIdx.x * blockDim.x + threadIdx.x;
  if (i < p.NF) { p.featb[i] = f2bf(p.feat[i]); return; }
  i -= p.NF;
  if (i < 1024 * 512) {
    int n = i >> 9, k = i & 511;
    p.wcatL1[i] = f2bf(n < 512 ? p.W1a[k * 512 + n] : p.W1at[k * 512 + n - 512]);
    return;
  }
  i -= 1024 * 512;
  if (i < 512 * 512) {
    int n = i >> 9, k = i & 511;
    p.wcat2[i] = f2bf(n < 256 ? p.W1b[k * 256 + n] : p.W1bt[k * 256 + n - 256]);
    return;
  }
  i -= 512 * 512;
  if (i < 512 * 512) {
    int n = i >> 9, k = i & 511;
    p.wcatLin[i] = f2bf(n < 256 ? p.W2[k * 256 + n] : p.W2t[k * 256 + n - 256]);
    return;
  }
  i -= 512 * 512;
  if (i < 256 * 256) {
    int n = i >> 8, k = i & 255;
    p.wtp[i] = f2bf(p.Wp[k * 256 + n]);
    return;
  }
  i -= 256 * 256;
  if (i < 1024) { p.bcatL1[i] = i < 512 ? p.b1a[i] : p.b1at[i - 512]; return; }
  i -= 1024;
  if (i < 512) { p.bcatGcn[i] = i < 256 ? p.b1b[i] : p.b1bt[i - 256]; return; }
  i -= 512;
  if (i < 512) { p.bcatLin[i] = i < 256 ? p.b2[i] : p.b2t[i - 256]; return; }
}

// ---------- bf16 MFMA GEMM: C[M,Nc] = A[M,K](lda) @ Wt[Nc,K]^T (+bias, opt relu) ----------
// asel>0: output cols >= asel read A columns [K, 2K).
// splitM>0: col c<256 -> outf row r; c>=256 -> row r+splitM (col c&255, stride 256); outb only c<256.
__global__ __launch_bounds__(256) void k_mgemm(
    const unsigned short* __restrict__ A, int lda,
    const unsigned short* __restrict__ Wt,
    const float* __restrict__ bias, float* __restrict__ outf, unsigned short* __restrict__ outb,
    int M, int K, int Nc, int relu, int asel, int splitM)
{
  __shared__ char smem[24576];     // A: 16 KB [128 rows][128 B], B: 8 KB [64 rows][128 B]
  char* As = smem;
  char* Bs = smem + 16384;
  const int tid = threadIdx.x;
  const int lane = tid & 63, w = tid >> 6;
  const int wr = w >> 1, wc = w & 1;
  const int bm = blockIdx.x * 128, bn = blockIdx.y * 64;
  const int aoff = (asel > 0 && bn >= asel) ? K : 0;
  const int srow = lane >> 3;                      // 0..7
  const int scol = ((lane & 7) ^ srow) << 3;       // pre-swizzled source col (elems)
  const int xr = (lane & 7) << 4;                  // read-side XOR (bytes)

  f32x4 acc[4][2];
  #pragma unroll
  for (int mi = 0; mi < 4; ++mi)
    #pragma unroll
    for (int nj = 0; nj < 2; ++nj)
      acc[mi][nj] = (f32x4){0.f, 0.f, 0.f, 0.f};

  for (int k0 = 0; k0 < K; k0 += 64) {
    #pragma unroll
    for (int i = 0; i < 4; ++i) {                  // A: 32 rows/wave
      int row = w * 32 + i * 8 + srow;
      int rg = bm + row; rg = rg < M ? rg : M - 1;
      GLOAD16(A + (size_t)rg * lda + aoff + k0 + scol, As + (w * 4096 + i * 1024));
    }
    #pragma unroll
    for (int i = 0; i < 2; ++i) {                  // B: 16 n-rows/wave
      int nrow = w * 16 + i * 8 + srow;
      GLOAD16(Wt + (size_t)(bn + nrow) * K + k0 + scol, Bs + (w * 2048 + i * 1024));
    }
    __syncthreads();
    #pragma unroll
    for (int ks = 0; ks < 2; ++ks) {
      const int kb = ks * 64 + ((lane >> 4) << 4);
      bf16x8 af[4], bfr[2];
      #pragma unroll
      for (int mi = 0; mi < 4; ++mi) {
        int row_l = wr * 64 + mi * 16 + (lane & 15);
        af[mi] = *(const bf16x8*)(As + row_l * 128 + (kb ^ xr));
      }
      #pragma unroll
      for (int nj = 0; nj < 2; ++nj) {
        int n_l = wc * 32 + nj * 16 + (lane & 15);
        bfr[nj] = *(const bf16x8*)(Bs + n_l * 128 + (kb ^ xr));
      }
      __builtin_amdgcn_s_setprio(1);
      #pragma unroll
      for (int mi = 0; mi < 4; ++mi)
        #pragma unroll
        for (int nj = 0; nj < 2; ++nj)
          acc[mi][nj] = __builtin_amdgcn_mfma_f32_16x16x32_bf16(af[mi], bfr[nj], acc[mi][nj], 0, 0, 0);
      __builtin_amdgcn_s_setprio(0);
    }
    __syncthreads();
  }

  #pragma unroll
  for (int mi = 0; mi < 4; ++mi) {
    #pragma unroll
    for (int j = 0; j < 4; ++j) {
      int r = bm + wr * 64 + mi * 16 + ((lane >> 4) << 2) + j;
      if (r >= M) continue;
      #pragma unroll
      for (int nj = 0; nj < 2; ++nj) {
        int c = bn + wc * 32 + nj * 16 + (lane & 15);
        float v = acc[mi][nj][j];
        if (bias) v += bias[c];
        if (relu) v = fmaxf(v, 0.f);
        if (splitM > 0) {
          int rr = r + (c >= 256 ? splitM : 0);
          if (outf) outf[(size_t)rr * 256 + (c & 255)] = v;
          if (outb && c < 256) outb[(size_t)r * 256 + c] = f2bf(v);
        } else {
          if (outf) outf[(size_t)r * Nc + c] = v;
          if (outb) outb[(size_t)r * Nc + c] = f2bf(v);
        }
      }
    }
  }
}

// ---------- GCN aggregate (bf16 h, F=512): one wave per node, 16B/lane, 8 accumulators ----------
__global__ __launch_bounds__(256) void k_agg(const unsigned short* __restrict__ h,
    const int* __restrict__ offs, const int* __restrict__ csr,
    const float* __restrict__ ns, const float* __restrict__ nd, const float* __restrict__ bias,
    float* __restrict__ outf, unsigned short* __restrict__ outb, int relu, int splitM)
{
  const int node = blockIdx.x * 4 + (threadIdx.x >> 6);
  const int lane = threadIdx.x & 63;
  const int j = lane * 8;
  const int s0 = offs[node], s1 = offs[node + 1];
  float a[8] = {};
  for (int k = s0; k < s1; ++k) {
    const int s = csr[k];
    const float w = ns[s];
    const u16x8 hv = *(const u16x8*)(h + (size_t)s * 512 + j);
    #pragma unroll
    for (int q = 0; q < 8; ++q) a[q] += b2f(hv[q]) * w;
  }
  const float ndv = nd[node];
  float o[8];
  #pragma unroll
  for (int q = 0; q < 8; ++q) {
    o[q] = a[q] * ndv;
    if (bias) o[q] += bias[j + q];
    if (relu) o[q] = fmaxf(o[q], 0.f);
  }
  if (splitM > 0) {
    const int rr = node + (j >= 256 ? splitM : 0);
    const int cc = j & 255;
    if (outf) {
      *(float4*)(outf + (size_t)rr * 256 + cc)     = (float4){o[0], o[1], o[2], o[3]};
      *(float4*)(outf + (size_t)rr * 256 + cc + 4) = (float4){o[4], o[5], o[6], o[7]};
    }
    if (outb && j < 256) {
      u16x8 ub;
      #pragma unroll
      for (int q = 0; q < 8; ++q) ub[q] = f2bf(o[q]);
      *(u16x8*)(outb + (size_t)node * 256 + j) = ub;
    }
  } else {
    if (outf) {
      *(float4*)(outf + (size_t)node * 512 + j)     = (float4){o[0], o[1], o[2], o[3]};
      *(float4*)(outf + (size_t)node * 512 + j + 4) = (float4){o[4], o[5], o[6], o[7]};
    }
    if (outb) {
      u16x8 ub;
      #pragma unroll
      for (int q = 0; q < 8; ++q) ub[q] = f2bf(o[q]);
      *(u16x8*)(outb + (size_t)node * 512 + j) = ub;
    }
  }
}

// ---------- row normalize x3 (fp32 in) -> bf16 out; blockIdx.y selects stream ----------
__global__ __launch_bounds__(256) void k_normrows3(
    const float* __restrict__ X0, unsigned short* __restrict__ O0,
    const float* __restrict__ X1, unsigned short* __restrict__ O1,
    const float* __restrict__ X2, unsigned short* __restrict__ O2, int Nrows)
{
  const float* X = blockIdx.y == 0 ? X0 : (blockIdx.y == 1 ? X1 : X2);
  unsigned short* O = blockIdx.y == 0 ? O0 : (blockIdx.y == 1 ? O1 : O2);
  const int wid = threadIdx.x >> 6, lane = threadIdx.x & 63;
  const int row = blockIdx.x * 4 + wid;
  if (row >= Nrows) return;
  const float4 v = ((const float4*)(X + (size_t)row * 256))[lane];
  float ss = v.x * v.x + v.y * v.y + v.z * v.z + v.w * v.w;
  #pragma unroll
  for (int m = 1; m < 64; m <<= 1) ss += __shfl_xor(ss, m);
  const float inv = 1.f / fmaxf(sqrtf(ss), 1e-12f);
  ushort4 u;
  u.x = f2bf(v.x * inv); u.y = f2bf(v.y * inv);
  u.z = f2bf(v.z * inv); u.w = f2bf(v.w * inv);
  ((ushort4*)(O + (size_t)row * 256))[lane] = u;
}

// ---------- edge scores via score-CSR: wave per dst node, 2 edges/iter (half-wave each) ----------
__global__ __launch_bounds__(256) void k_edge(
    const unsigned short* __restrict__ zun1, const unsigned short* __restrict__ zun2,
    const unsigned short* __restrict__ qb,
    const int* __restrict__ offs_s, const int* __restrict__ csr_es,
    const float* __restrict__ tau1p, const float* __restrict__ tau2p,
    const float* __restrict__ negs1, const float* __restrict__ negs2,
    float* __restrict__ pos1, float* __restrict__ neg1,
    float* __restrict__ pos2, float* __restrict__ neg2, int N)
{
  const int node = blockIdx.x * 4 + (threadIdx.x >> 6);
  if (node >= N) return;
  const int z = blockIdx.y;
  const unsigned short* un = (z ? zun2 : zun1) + (size_t)N * 256;
  const unsigned short* q = qb + (size_t)z * N * 256;
  const float inv_tau = 1.f / (z ? tau2p[0] : tau1p[0]);
  const float nsd = (z ? negs2 : negs1)[node];
  float* pos = z ? pos2 : pos1;
  float* neg = z ? neg2 : neg1;
  const int lane = threadIdx.x & 63;
  const int l = lane & 31, h = lane >> 5;
  const u16x8 qv = *(const u16x8*)(q + (size_t)node * 256 + l * 8);
  float qf[8];
  #pragma unroll
  for (int i = 0; i < 8; ++i) qf[i] = b2f(qv[i]);
  const int s0 = offs_s[node], s1 = offs_s[node + 1];
  float pacc = 0.f, nacc = 0.f;
  for (int k = s0 + h; k < s1; k += 2) {
    const int s = csr_es[k];
    const u16x8 av = *(const u16x8*)(un + (size_t)s * 256 + l * 8);
    float dot = 0.f;
    #pragma unroll
    for (int i = 0; i < 8; ++i) dot += b2f(av[i]) * qf[i];
    #pragma unroll
    for (int m = 1; m < 32; m <<= 1) dot += __shfl_xor(dot, m);
    if (l == 0) {
      const float sv = dot * inv_tau;
      pacc += sv;
      nacc += logf(nsd + __expf(sv));
    }
  }
  pacc += __shfl_xor(pacc, 32);
  nacc += __shfl_xor(nacc, 32);
  if (lane == 0) { pos[node] = pacc; neg[node] = nacc; }
}

// ---------- neg_sim: 4 i-tiles/wave, 4 waves/block, 32-row j-tiles,
//            dbuf 2x16KB LDS (global_load_lds), XCD-swizzled flat grid ----------
#define NEG_JSPLIT 16
#define NEG_TILES 4
__global__ __launch_bounds__(256) void k_negsim(
    const unsigned short* __restrict__ zun1, const unsigned short* __restrict__ zun2,
    const float* __restrict__ tau1p, const float* __restrict__ tau2p,
    float* __restrict__ negs1, float* __restrict__ negs2, int N, int ngroups)
{
  __shared__ char smem[32768];     // 2 x 16KB j-tiles (32 rows x 512B, XOR-swizzled layout)
  // bijective XCD swizzle (T1, m204): consecutive work ids land on the same XCD
  const int nwg = gridDim.x;
  const int q8 = nwg >> 3, r8 = nwg & 7;
  const int xcd = blockIdx.x & 7, bidx = blockIdx.x >> 3;
  const int swz = (xcd < r8 ? xcd * (q8 + 1) : r8 * (q8 + 1) + (xcd - r8) * q8) + bidx;
  const int bx = swz % ngroups;
  const int btmp = swz / ngroups;
  const int by = btmp % NEG_JSPLIT;
  const int z = btmp / NEG_JSPLIT;

  const int tid = threadIdx.x;
  const int lane = tid & 63, wid = tid >> 6;
  const unsigned short* zun = z ? zun2 : zun1;
  float* negsim = z ? negs2 : negs1;
  // exp(x/tau) = exp2(x * log2(e)/tau): one v_mul + v_exp per element
  const float KE = 1.4426950408889634f / (z ? tau2p[0] : tau1p[0]);
  const int ntiles = N >> 4;
  int itv[NEG_TILES]; bool vv[NEG_TILES];
  #pragma unroll
  for (int t = 0; t < NEG_TILES; ++t) {
    int it = bx * (4 * NEG_TILES) + wid * NEG_TILES + t;
    vv[t] = it < ntiles;
    itv[t] = vv[t] ? it : (ntiles - 1);
  }

  bf16x8 afrag[NEG_TILES][8];
  #pragma unroll
  for (int t = 0; t < NEG_TILES; ++t) {
    const unsigned short* r = zun + (size_t)((itv[t] << 4) + (lane & 15)) * 256 + ((lane >> 4) << 3);
    #pragma unroll
    for (int ks = 0; ks < 8; ++ks)
      afrag[t][ks] = *(const bf16x8*)(r + ks * 32);
  }

  const int total = 2 * N;
  const int chunk = ((total + NEG_JSPLIT * 32 - 1) / (NEG_JSPLIT * 32)) * 32;
  const int jbeg = by * chunk;
  const int jend = min(total, jbeg + chunk);
  if (jbeg >= jend) return;

  float psum[NEG_TILES][4];
  #pragma unroll
  for (int t = 0; t < NEG_TILES; ++t)
    #pragma unroll
    for (int j = 0; j < 4; ++j) psum[t][j] = 0.f;

  // stage a 32-row tile: LDS[r][c] = G[j0+r][c ^ (r&7)] (16B units); linear dest (rule #21)
  auto stage = [&](int buf, int j0) {
    #pragma unroll
    for (int i = 0; i < 4; ++i) {
      int idx = tid + 256 * i;
      int r = idx >> 5, c = idx & 31;
      int g = j0 + r; g = g < total ? g : total - 1;
      int cp = c ^ (r & 7);
      GLOAD16(zun + (size_t)g * 256 + cp * 8, smem + buf * 16384 + r * 512 + c * 16);
    }
  };

  const int rxor = (lane & 7) << 4;
  const int kcol = (lane >> 4) << 4;
  int cur = 0;
  stage(0, jbeg);
  __syncthreads();                         // drains vmcnt + barrier
  for (int j0 = jbeg; j0 < jend; j0 += 32) {
    if (j0 + 32 < jend) stage(cur ^ 1, j0 + 32);   // async, overlaps compute below
    const int rows = min(32, jend - j0);   // multiple of 16
    const int nsub = rows >> 4;
    const char* base = smem + cur * 16384;
    for (int sub = 0; sub < nsub; ++sub) {
      const char* bb = base + (sub * 16 + (lane & 15)) * 512;
      f32x4 acc[NEG_TILES];
      #pragma unroll
      for (int t = 0; t < NEG_TILES; ++t) acc[t] = (f32x4){0.f, 0.f, 0.f, 0.f};
      __builtin_amdgcn_s_setprio(1);
      #pragma unroll
      for (int ks = 0; ks < 8; ++ks) {
        bf16x8 bfrag = *(const bf16x8*)(bb + ((kcol + ks * 64) ^ rxor));
        #pragma unroll
        for (int t = 0; t < NEG_TILES; ++t)
          acc[t] = __builtin_amdgcn_mfma_f32_16x16x32_bf16(afrag[t][ks], bfrag, acc[t], 0, 0, 0);
      }
      __builtin_amdgcn_s_setprio(0);
      #pragma unroll
      for (int t = 0; t < NEG_TILES; ++t)
        #pragma unroll
        for (int j = 0; j < 4; ++j)
          psum[t][j] += exp2f(acc[t][j] * KE);
    }
    __syncthreads();                       // drains next-tile GLOADs; protects cur buffer
    cur ^= 1;
  }
  #pragma unroll
  for (int t = 0; t < NEG_TILES; ++t)
    #pragma unroll
    for (int j = 0; j < 4; ++j) {
      float x = psum[t][j];
      x += __shfl_xor(x, 1);
      x += __shfl_xor(x, 2);
      x += __shfl_xor(x, 4);
      x += __shfl_xor(x, 8);
      if (vv[t] && (lane & 15) == 0)
        atomicAdd(&negsim[(itv[t] << 4) + ((lane >> 4) << 2) + j], x);
    }
}

// ---------- loss = mean(-pos1+neg1)/cnt + mean(-pos2+neg2)/cnt ----------
__global__ __launch_bounds__(1024) void k_loss(
    const float* __restrict__ pos1, const float* __restrict__ neg1,
    const float* __restrict__ pos2, const float* __restrict__ neg2,
    const int* __restrict__ cnt, int N, float* __restrict__ out)
{
  __shared__ float lds[1024];
  float s = 0.f;
  for (int i = threadIdx.x; i < N; i += 1024) {
    float denom = fmaxf((float)cnt[i], 1.f);
    s += ((-pos1[i] + neg1[i]) + (-pos2[i] + neg2[i])) / denom;
  }
  lds[threadIdx.x] = s;
  __syncthreads();
  for (int o = 512; o > 0; o >>= 1) {
    if (threadIdx.x < o) lds[threadIdx.x] += lds[threadIdx.x + o];
    __syncthreads();
  }
  if (threadIdx.x == 0) out[0] = lds[0] / (float)N;
}

extern "C" void kernel_launch(void* const* d_in, const int* in_sizes, int n_in,
                              void* d_out, int out_size, void* d_ws, size_t ws_size,
                              hipStream_t stream)
{
  const float* feat  = (const float*)d_in[0];
  const int* src_g   = (const int*)d_in[1];
  const int* dst_g   = (const int*)d_in[2];
  const int* src_s   = (const int*)d_in[3];
  const int* dst_s   = (const int*)d_in[4];
  const float* tau1  = (const float*)d_in[5];
  const float* tau2  = (const float*)d_in[6];
  const float* W1a   = (const float*)d_in[7];
  const float* b1a   = (const float*)d_in[8];
  const float* W1b   = (const float*)d_in[9];
  const float* b1b   = (const float*)d_in[10];
  const float* W1a_t = (const float*)d_in[11];
  const float* b1a_t = (const float*)d_in[12];
  const float* W1b_t = (const float*)d_in[13];
  const float* b1b_t = (const float*)d_in[14];
  const float* W2    = (const float*)d_in[15];
  const float* b2    = (const float*)d_in[16];
  const float* W2_t  = (const float*)d_in[17];
  const float* b2_t  = (const float*)d_in[18];
  const float* Wp    = (const float*)d_in[19];
  const float* bp    = (const float*)d_in[20];

  const int N = in_sizes[0] / 512;
  const int E = in_sizes[1];

  float* out  = (float*)d_out;
  float* v1u1 = out;                               // rows 0..2N-1 (v1 then u1)
  float* v2u2 = out + (size_t)2 * N * 256;         // rows 0..2N-1 (v2 then u2)
  float* loss = out + (size_t)4 * N * 256;

  char* ws = (char*)d_ws;
  size_t off = 0;
  auto alloc = [&](size_t bytes) -> char* {
    char* p = ws + off;
    off += (bytes + 255) & ~(size_t)255;
    return p;
  };
  int* zbase    = (int*)alloc((size_t)11 * N * 4);   // zeroed region
  int* deg_og   = zbase;
  int* deg_ig   = zbase + N;
  int* cnt_s    = zbase + 2 * N;
  int* cursor   = zbase + 3 * N;
  int* cursor_s = zbase + 4 * N;
  float* pos1   = (float*)(zbase + 5 * N);
  float* neg1   = (float*)(zbase + 6 * N);
  float* pos2   = (float*)(zbase + 7 * N);
  float* neg2   = (float*)(zbase + 8 * N);
  float* negs1  = (float*)(zbase + 9 * N);
  float* negs2  = (float*)(zbase + 10 * N);
  int* offs    = (int*)alloc((size_t)(N + 1) * 4);
  int* offs_s  = (int*)alloc((size_t)(N + 1) * 4);
  int* csr_src = (int*)alloc((size_t)E * 4);
  int* csr_es  = (int*)alloc((size_t)E * 4);
  float* ns    = (float*)alloc((size_t)N * 4);
  float* nd    = (float*)alloc((size_t)N * 4);
  unsigned short* featb   = (unsigned short*)alloc((size_t)N * 512 * 2);
  unsigned short* wcatL1  = (unsigned short*)alloc((size_t)1024 * 512 * 2);
  unsigned short* wcat2   = (unsigned short*)alloc((size_t)512 * 512 * 2);
  unsigned short* wcatLin = (unsigned short*)alloc((size_t)512 * 512 * 2);
  unsigned short* wtp     = (unsigned short*)alloc((size_t)256 * 256 * 2);
  float* bcatL1  = (float*)alloc(1024 * 4);
  float* bcatGcn = (float*)alloc(512 * 4);
  float* bcatLin = (float*)alloc(512 * 4);
  char* BUF_H = alloc((size_t)N * 2048);  // hcat [N][1024] bf16 -> q_raw [2N][256] f32
  char* BUF_A = alloc((size_t)N * 1024);  // Xaggb -> g2cat -> qb
  char* BUF_B = alloc((size_t)N * 1024);  // zun1 [2N][256] bf16
  char* BUF_C = alloc((size_t)N * 1024);  // zun2
  char* BUF_E = alloc((size_t)N * 1024);  // v1b || v2b
  if (off > ws_size) return;  // workspace too small -> visible failure

  unsigned short* Xaggb = (unsigned short*)BUF_A;
  unsigned short* hcat  = (unsigned short*)BUF_H;
  unsigned short* g2cat = (unsigned short*)BUF_A;            // Xaggb dead after gemmL1
  unsigned short* v1b   = (unsigned short*)BUF_E;
  float*          q_raw = (float*)BUF_H;                     // hcat dead after gemmL2
  unsigned short* qb    = (unsigned short*)BUF_A;            // g2cat dead after aggdual
  unsigned short* zun1  = (unsigned short*)BUF_B;
  unsigned short* zun2  = (unsigned short*)BUF_C;

  const int eb = (E + 255) / 256;
  const int gmx = (N + 127) / 128;
  const int gqx = (2 * N + 127) / 128;
  const int ntiles = N / 16;
  const int ngroups = (ntiles + 4 * NEG_TILES - 1) / (4 * NEG_TILES);
  const int negblocks = ngroups * NEG_JSPLIT * 2;
  const dim3 edgegrid((N + 3) / 4, 2);
  const dim3 nrmgrid((2 * N + 3) / 4, 3);
  const int scanblocks = 2 + (N + 1023) / 1024;

  hipMemsetAsync(zbase, 0, (size_t)11 * N * 4, stream);
  k_count<<<eb, 256, 0, stream>>>(src_g, dst_g, dst_s, deg_og, deg_ig, cnt_s, E);
  k_scan<<<scanblocks, 1024, 0, stream>>>(deg_ig, offs, cnt_s, offs_s,
                                          deg_og, deg_ig, ns, nd, N);
  k_fill<<<dim3(eb, 2), 256, 0, stream>>>(src_g, dst_g, offs, cursor, csr_src,
                                          src_s, dst_s, offs_s, cursor_s, csr_es, E);

  PrepArgs pa;
  pa.feat = feat; pa.W1a = W1a; pa.W1at = W1a_t; pa.W1b = W1b; pa.W1bt = W1b_t;
  pa.W2 = W2; pa.W2t = W2_t; pa.Wp = Wp;
  pa.b1a = b1a; pa.b1at = b1a_t; pa.b1b = b1b; pa.b1bt = b1b_t; pa.b2 = b2; pa.b2t = b2_t;
  pa.featb = featb; pa.wcatL1 = wcatL1; pa.wcat2 = wcat2; pa.wcatLin = wcatLin; pa.wtp = wtp;
  pa.bcatL1 = bcatL1; pa.bcatGcn = bcatGcn; pa.bcatLin = bcatLin;
  pa.NF = N * 512;
  const int ptotal = pa.NF + 1024 * 512 + 512 * 512 + 512 * 512 + 256 * 256 + 1024 + 512 + 512;
  k_prep<<<(ptotal + 255) / 256, 256, 0, stream>>>(pa);

  // Shared layer-1 aggregate (agg(X@W) == agg(X)@W), then concat GEMMs
  k_agg<<<N / 4, 256, 0, stream>>>(featb, offs, csr_src, ns, nd, nullptr, nullptr, Xaggb, 0, 0);
  k_mgemm<<<dim3(gmx, 16), 256, 0, stream>>>(Xaggb, 512, wcatL1, bcatL1, nullptr, hcat,
                                             N, 512, 1024, 1, 0, 0);
  k_mgemm<<<dim3(gmx, 8), 256, 0, stream>>>(hcat, 1024, wcat2, nullptr, nullptr, g2cat,
                                            N, 512, 512, 0, 256, 0);
  k_agg<<<N / 4, 256, 0, stream>>>(g2cat, offs, csr_src, ns, nd, bcatGcn, v1u1, v1b, 0, N);
  k_mgemm<<<dim3(gmx, 8), 256, 0, stream>>>(featb, 512, wcatLin, bcatLin, v2u2,
                                            (unsigned short*)BUF_E + (size_t)N * 256,
                                            N, 512, 512, 0, 0, N);
  // projector for both branches in one GEMM (A = v1b||v2b, 2N rows)
  k_mgemm<<<dim3(gqx, 4), 256, 0, stream>>>((unsigned short*)BUF_E, 256, wtp, bp, q_raw, nullptr,
                                            2 * N, 256, 256, 0, 0, 0);

  // normalizations (3 streams x 2N rows, one dispatch)
  k_normrows3<<<nrmgrid, 256, 0, stream>>>(v1u1, zun1, v2u2, zun2, q_raw, qb, 2 * N);

  // scores (both branches per dispatch)
  k_negsim<<<negblocks, 256, 0, stream>>>(zun1, zun2, tau1, tau2, negs1, negs2, N, ngroups);
  k_edge<<<edgegrid, 256, 0, stream>>>(zun1, zun2, qb, offs_s, csr_es, tau1, tau2,
                                       negs1, negs2, pos1, neg1, pos2, neg2, N);
  k_loss<<<1, 1024, 0, stream>>>(pos1, neg1, pos2, neg2, cnt_s, N, loss);
}

// Round 13
// 610.224 us; speedup vs baseline: 1.0748x; 1.0748x over previous
//
#include <hip/hip_runtime.h>

typedef __bf16 bf16x8 __attribute__((ext_vector_type(8)));
typedef float f32x4 __attribute__((ext_vector_type(4)));
typedef unsigned short u16x8 __attribute__((ext_vector_type(8)));

#define GLOAD16(gp, lp) __builtin_amdgcn_global_load_lds( \
    (const __attribute__((address_space(1))) void*)(gp), \
    (__attribute__((address_space(3))) void*)(lp), 16, 0, 0)

__device__ __forceinline__ unsigned short f2bf(float f) {
  union { float f; unsigned u; } c; c.f = f;
  unsigned u = c.u;
  u = (u + 0x7fffu + ((u >> 16) & 1u)) >> 16;
  return (unsigned short)u;
}
__device__ __forceinline__ float b2f(unsigned short u) {
  union { unsigned u; float f; } c; c.u = ((unsigned)u) << 16; return c.f;
}

// ---------- graph prep ----------
__global__ void k_count(const int* __restrict__ src_g, const int* __restrict__ dst_g,
                        const int* __restrict__ dst_s,
                        int* deg_og, int* deg_ig, int* cnt_s, int E)
{
  int e = blockIdx.x * blockDim.x + threadIdx.x;
  if (e >= E) return;
  atomicAdd(&deg_og[src_g[e]], 1);
  atomicAdd(&deg_ig[dst_g[e]], 1);
  atomicAdd(&cnt_s[dst_s[e]], 1);
}

// dual scan (blocks 0,1) + degree norms (blocks >= 2)
__global__ __launch_bounds__(1024) void k_scan(const int* __restrict__ deg0, int* __restrict__ offs0,
                                               const int* __restrict__ deg1, int* __restrict__ offs1,
                                               const int* __restrict__ deg_og, const int* __restrict__ deg_ig,
                                               float* __restrict__ ns, float* __restrict__ nd, int N)
{
  if (blockIdx.x >= 2) {
    int i = (blockIdx.x - 2) * 1024 + threadIdx.x;
    if (i < N) {
      int a = deg_og[i]; ns[i] = a > 0 ? rsqrtf((float)a) : 0.f;
      int b = deg_ig[i]; nd[i] = b > 0 ? rsqrtf((float)b) : 0.f;
    }
    return;
  }
  const int* deg = blockIdx.x ? deg1 : deg0;
  int* offs = blockIdx.x ? offs1 : offs0;
  __shared__ int part[1024];
  const int t = threadIdx.x;
  const int CH = (N + 1023) / 1024;
  const int b = t * CH;
  int s = 0;
  for (int i = 0; i < CH; ++i) {
    int idx = b + i;
    s += (idx < N) ? deg[idx] : 0;
  }
  part[t] = s;
  __syncthreads();
  for (int o = 1; o < 1024; o <<= 1) {
    int v = (t >= o) ? part[t - o] : 0;
    __syncthreads();
    part[t] += v;
    __syncthreads();
  }
  int run = (t == 0) ? 0 : part[t - 1];
  if (t == 0) offs[0] = 0;
  for (int i = 0; i < CH; ++i) {
    int idx = b + i;
    if (idx < N) { run += deg[idx]; offs[idx + 1] = run; }
  }
}

// dual fill: blockIdx.y==0 -> graph edges; ==1 -> score edges
__global__ void k_fill(const int* __restrict__ srcA, const int* __restrict__ dstA,
                       const int* __restrict__ offsA, int* curA, int* __restrict__ outA,
                       const int* __restrict__ srcB, const int* __restrict__ dstB,
                       const int* __restrict__ offsB, int* curB, int* __restrict__ outB, int E)
{
  int e = blockIdx.x * blockDim.x + threadIdx.x;
  if (e >= E) return;
  if (blockIdx.y == 0) {
    int d = dstA[e];
    int p = atomicAdd(&curA[d], 1);
    outA[offsA[d] + p] = srcA[e];
  } else {
    int d = dstB[e];
    int p = atomicAdd(&curB[d], 1);
    outB[offsB[d] + p] = srcB[e];
  }
}

// ---------- one-shot prep: feat cast + all weight transposes/concats + bias concats ----------
struct PrepArgs {
  const float *feat, *W1a, *W1at, *W1b, *W1bt, *W2, *W2t, *Wp;
  const float *b1a, *b1at, *b1b, *b1bt, *b2, *b2t;
  unsigned short *featb, *wcatL1, *wcat2, *wcatLin, *wtp;
  float *bcatL1, *bcatGcn, *bcatLin;
  int NF;
};
__global__ void k_prep(PrepArgs p)
{
  int i = blockIdx.x * blockDim.x + threadIdx.x;
  if (i < p.NF) { p.featb[i] = f2bf(p.feat[i]); return; }
  i -= p.NF;
  if (i < 1024 * 512) {
    int n = i >> 9, k = i & 511;
    p.wcatL1[i] = f2bf(n < 512 ? p.W1a[k * 512 + n] : p.W1at[k * 512 + n - 512]);
    return;
  }
  i -= 1024 * 512;
  if (i < 512 * 512) {
    int n = i >> 9, k = i & 511;
    p.wcat2[i] = f2bf(n < 256 ? p.W1b[k * 256 + n] : p.W1bt[k * 256 + n - 256]);
    return;
  }
  i -= 512 * 512;
  if (i < 512 * 512) {
    int n = i >> 9, k = i & 511;
    p.wcatLin[i] = f2bf(n < 256 ? p.W2[k * 256 + n] : p.W2t[k * 256 + n - 256]);
    return;
  }
  i -= 512 * 512;
  if (i < 256 * 256) {
    int n = i >> 8, k = i & 255;
    p.wtp[i] = f2bf(p.Wp[k * 256 + n]);
    return;
  }
  i -= 256 * 256;
  if (i < 1024) { p.bcatL1[i] = i < 512 ? p.b1a[i] : p.b1at[i - 512]; return; }
  i -= 1024;
  if (i < 512) { p.bcatGcn[i] = i < 256 ? p.b1b[i] : p.b1bt[i - 256]; return; }
  i -= 512;
  if (i < 512) { p.bcatLin[i] = i < 256 ? p.b2[i] : p.b2t[i - 256]; return; }
}

// ---------- bf16 MFMA GEMM: C[M,Nc] = A[M,K](lda) @ Wt[Nc,K]^T (+bias, opt relu) ----------
// asel>0: output cols >= asel read A columns [K, 2K).
// splitM>0: col c<256 -> outf row r; c>=256 -> row r+splitM (col c&255, stride 256); outb only c<256.
__global__ __launch_bounds__(256) void k_mgemm(
    const unsigned short* __restrict__ A, int lda,
    const unsigned short* __restrict__ Wt,
    const float* __restrict__ bias, float* __restrict__ outf, unsigned short* __restrict__ outb,
    int M, int K, int Nc, int relu, int asel, int splitM)
{
  __shared__ char smem[24576];     // A: 16 KB [128 rows][128 B], B: 8 KB [64 rows][128 B]
  char* As = smem;
  char* Bs = smem + 16384;
  const int tid = threadIdx.x;
  const int lane = tid & 63, w = tid >> 6;
  const int wr = w >> 1, wc = w & 1;
  const int bm = blockIdx.x * 128, bn = blockIdx.y * 64;
  const int aoff = (asel > 0 && bn >= asel) ? K : 0;
  const int srow = lane >> 3;                      // 0..7
  const int scol = ((lane & 7) ^ srow) << 3;       // pre-swizzled source col (elems)
  const int xr = (lane & 7) << 4;                  // read-side XOR (bytes)

  f32x4 acc[4][2];
  #pragma unroll
  for (int mi = 0; mi < 4; ++mi)
    #pragma unroll
    for (int nj = 0; nj < 2; ++nj)
      acc[mi][nj] = (f32x4){0.f, 0.f, 0.f, 0.f};

  for (int k0 = 0; k0 < K; k0 += 64) {
    #pragma unroll
    for (int i = 0; i < 4; ++i) {                  // A: 32 rows/wave
      int row = w * 32 + i * 8 + srow;
      int rg = bm + row; rg = rg < M ? rg : M - 1;
      GLOAD16(A + (size_t)rg * lda + aoff + k0 + scol, As + (w * 4096 + i * 1024));
    }
    #pragma unroll
    for (int i = 0; i < 2; ++i) {                  // B: 16 n-rows/wave
      int nrow = w * 16 + i * 8 + srow;
      GLOAD16(Wt + (size_t)(bn + nrow) * K + k0 + scol, Bs + (w * 2048 + i * 1024));
    }
    __syncthreads();
    #pragma unroll
    for (int ks = 0; ks < 2; ++ks) {
      const int kb = ks * 64 + ((lane >> 4) << 4);
      bf16x8 af[4], bfr[2];
      #pragma unroll
      for (int mi = 0; mi < 4; ++mi) {
        int row_l = wr * 64 + mi * 16 + (lane & 15);
        af[mi] = *(const bf16x8*)(As + row_l * 128 + (kb ^ xr));
      }
      #pragma unroll
      for (int nj = 0; nj < 2; ++nj) {
        int n_l = wc * 32 + nj * 16 + (lane & 15);
        bfr[nj] = *(const bf16x8*)(Bs + n_l * 128 + (kb ^ xr));
      }
      __builtin_amdgcn_s_setprio(1);
      #pragma unroll
      for (int mi = 0; mi < 4; ++mi)
        #pragma unroll
        for (int nj = 0; nj < 2; ++nj)
          acc[mi][nj] = __builtin_amdgcn_mfma_f32_16x16x32_bf16(af[mi], bfr[nj], acc[mi][nj], 0, 0, 0);
      __builtin_amdgcn_s_setprio(0);
    }
    __syncthreads();
  }

  #pragma unroll
  for (int mi = 0; mi < 4; ++mi) {
    #pragma unroll
    for (int j = 0; j < 4; ++j) {
      int r = bm + wr * 64 + mi * 16 + ((lane >> 4) << 2) + j;
      if (r >= M) continue;
      #pragma unroll
      for (int nj = 0; nj < 2; ++nj) {
        int c = bn + wc * 32 + nj * 16 + (lane & 15);
        float v = acc[mi][nj][j];
        if (bias) v += bias[c];
        if (relu) v = fmaxf(v, 0.f);
        if (splitM > 0) {
          int rr = r + (c >= 256 ? splitM : 0);
          if (outf) outf[(size_t)rr * 256 + (c & 255)] = v;
          if (outb && c < 256) outb[(size_t)r * 256 + c] = f2bf(v);
        } else {
          if (outf) outf[(size_t)r * Nc + c] = v;
          if (outb) outb[(size_t)r * Nc + c] = f2bf(v);
        }
      }
    }
  }
}

// ---------- GCN aggregate (bf16 h, F=512): one wave per node, 16B/lane, 8 accumulators ----------
__global__ __launch_bounds__(256) void k_agg(const unsigned short* __restrict__ h,
    const int* __restrict__ offs, const int* __restrict__ csr,
    const float* __restrict__ ns, const float* __restrict__ nd, const float* __restrict__ bias,
    float* __restrict__ outf, unsigned short* __restrict__ outb, int relu, int splitM)
{
  const int node = blockIdx.x * 4 + (threadIdx.x >> 6);
  const int lane = threadIdx.x & 63;
  const int j = lane * 8;
  const int s0 = offs[node], s1 = offs[node + 1];
  float a[8] = {};
  for (int k = s0; k < s1; ++k) {
    const int s = csr[k];
    const float w = ns[s];
    const u16x8 hv = *(const u16x8*)(h + (size_t)s * 512 + j);
    #pragma unroll
    for (int q = 0; q < 8; ++q) a[q] += b2f(hv[q]) * w;
  }
  const float ndv = nd[node];
  float o[8];
  #pragma unroll
  for (int q = 0; q < 8; ++q) {
    o[q] = a[q] * ndv;
    if (bias) o[q] += bias[j + q];
    if (relu) o[q] = fmaxf(o[q], 0.f);
  }
  if (splitM > 0) {
    const int rr = node + (j >= 256 ? splitM : 0);
    const int cc = j & 255;
    if (outf) {
      *(float4*)(outf + (size_t)rr * 256 + cc)     = (float4){o[0], o[1], o[2], o[3]};
      *(float4*)(outf + (size_t)rr * 256 + cc + 4) = (float4){o[4], o[5], o[6], o[7]};
    }
    if (outb && j < 256) {
      u16x8 ub;
      #pragma unroll
      for (int q = 0; q < 8; ++q) ub[q] = f2bf(o[q]);
      *(u16x8*)(outb + (size_t)node * 256 + j) = ub;
    }
  } else {
    if (outf) {
      *(float4*)(outf + (size_t)node * 512 + j)     = (float4){o[0], o[1], o[2], o[3]};
      *(float4*)(outf + (size_t)node * 512 + j + 4) = (float4){o[4], o[5], o[6], o[7]};
    }
    if (outb) {
      u16x8 ub;
      #pragma unroll
      for (int q = 0; q < 8; ++q) ub[q] = f2bf(o[q]);
      *(u16x8*)(outb + (size_t)node * 512 + j) = ub;
    }
  }
}

// ---------- row normalize x3 (fp32 in) -> bf16 out; blockIdx.y selects stream ----------
__global__ __launch_bounds__(256) void k_normrows3(
    const float* __restrict__ X0, unsigned short* __restrict__ O0,
    const float* __restrict__ X1, unsigned short* __restrict__ O1,
    const float* __restrict__ X2, unsigned short* __restrict__ O2, int Nrows)
{
  const float* X = blockIdx.y == 0 ? X0 : (blockIdx.y == 1 ? X1 : X2);
  unsigned short* O = blockIdx.y == 0 ? O0 : (blockIdx.y == 1 ? O1 : O2);
  const int wid = threadIdx.x >> 6, lane = threadIdx.x & 63;
  const int row = blockIdx.x * 4 + wid;
  if (row >= Nrows) return;
  const float4 v = ((const float4*)(X + (size_t)row * 256))[lane];
  float ss = v.x * v.x + v.y * v.y + v.z * v.z + v.w * v.w;
  #pragma unroll
  for (int m = 1; m < 64; m <<= 1) ss += __shfl_xor(ss, m);
  const float inv = 1.f / fmaxf(sqrtf(ss), 1e-12f);
  ushort4 u;
  u.x = f2bf(v.x * inv); u.y = f2bf(v.y * inv);
  u.z = f2bf(v.z * inv); u.w = f2bf(v.w * inv);
  ((ushort4*)(O + (size_t)row * 256))[lane] = u;
}

// ---------- edge scores via score-CSR: wave per dst node, 2 edges/iter (half-wave each) ----------
__global__ __launch_bounds__(256) void k_edge(
    const unsigned short* __restrict__ zun1, const unsigned short* __restrict__ zun2,
    const unsigned short* __restrict__ qb,
    const int* __restrict__ offs_s, const int* __restrict__ csr_es,
    const float* __restrict__ tau1p, const float* __restrict__ tau2p,
    const float* __restrict__ negs1, const float* __restrict__ negs2,
    float* __restrict__ pos1, float* __restrict__ neg1,
    float* __restrict__ pos2, float* __restrict__ neg2, int N)
{
  const int node = blockIdx.x * 4 + (threadIdx.x >> 6);
  if (node >= N) return;
  const int z = blockIdx.y;
  const unsigned short* un = (z ? zun2 : zun1) + (size_t)N * 256;
  const unsigned short* q = qb + (size_t)z * N * 256;
  const float inv_tau = 1.f / (z ? tau2p[0] : tau1p[0]);
  const float nsd = (z ? negs2 : negs1)[node];
  float* pos = z ? pos2 : pos1;
  float* neg = z ? neg2 : neg1;
  const int lane = threadIdx.x & 63;
  const int l = lane & 31, h = lane >> 5;
  const u16x8 qv = *(const u16x8*)(q + (size_t)node * 256 + l * 8);
  float qf[8];
  #pragma unroll
  for (int i = 0; i < 8; ++i) qf[i] = b2f(qv[i]);
  const int s0 = offs_s[node], s1 = offs_s[node + 1];
  float pacc = 0.f, nacc = 0.f;
  for (int k = s0 + h; k < s1; k += 2) {
    const int s = csr_es[k];
    const u16x8 av = *(const u16x8*)(un + (size_t)s * 256 + l * 8);
    float dot = 0.f;
    #pragma unroll
    for (int i = 0; i < 8; ++i) dot += b2f(av[i]) * qf[i];
    #pragma unroll
    for (int m = 1; m < 32; m <<= 1) dot += __shfl_xor(dot, m);
    if (l == 0) {
      const float sv = dot * inv_tau;
      pacc += sv;
      nacc += logf(nsd + __expf(sv));
    }
  }
  pacc += __shfl_xor(pacc, 32);
  nacc += __shfl_xor(nacc, 32);
  if (lane == 0) { pos[node] = pacc; neg[node] = nacc; }
}

// ---------- neg_sim (R5 best body): 4 i-tiles/wave, 4 waves/block, 64-row j-tiles,
//            dbuf 2x32KB LDS via global_load_lds, __expf, plain __syncthreads ----------
#define NEG_JSPLIT 32
#define NEG_TILES 4
__global__ __launch_bounds__(256) void k_negsim(
    const unsigned short* __restrict__ zun1, const unsigned short* __restrict__ zun2,
    const float* __restrict__ tau1p, const float* __restrict__ tau2p,
    float* __restrict__ negs1, float* __restrict__ negs2, int N)
{
  __shared__ char smem[65536];     // 2 x 32KB j-tiles (64 rows x 512B, XOR-swizzled layout)
  const int tid = threadIdx.x;
  const int lane = tid & 63, wid = tid >> 6;
  const int z = blockIdx.z;
  const unsigned short* zun = z ? zun2 : zun1;
  float* negsim = z ? negs2 : negs1;
  const float k_exp = 1.0f / (z ? tau2p[0] : tau1p[0]);
  const int ntiles = N >> 4;
  const int quad = blockIdx.x * 4 + wid;
  int itv[NEG_TILES]; bool vv[NEG_TILES];
  #pragma unroll
  for (int t = 0; t < NEG_TILES; ++t) {
    int it = quad * NEG_TILES + t;
    vv[t] = it < ntiles;
    itv[t] = vv[t] ? it : (ntiles - 1);
  }

  bf16x8 afrag[NEG_TILES][8];
  #pragma unroll
  for (int t = 0; t < NEG_TILES; ++t) {
    const unsigned short* r = zun + (size_t)((itv[t] << 4) + (lane & 15)) * 256 + ((lane >> 4) << 3);
    #pragma unroll
    for (int ks = 0; ks < 8; ++ks)
      afrag[t][ks] = *(const bf16x8*)(r + ks * 32);
  }

  const int total = 2 * N;
  const int chunk = ((total + NEG_JSPLIT * 64 - 1) / (NEG_JSPLIT * 64)) * 64;
  const int jbeg = blockIdx.y * chunk;
  const int jend = min(total, jbeg + chunk);
  if (jbeg >= jend) return;

  float psum[NEG_TILES][4];
  #pragma unroll
  for (int t = 0; t < NEG_TILES; ++t)
    #pragma unroll
    for (int j = 0; j < 4; ++j) psum[t][j] = 0.f;

  // stage: LDS[r][c] = G[j0+r][c ^ (r&7)]  (16B units); dest linear per lane (rule #21)
  auto stage = [&](int buf, int j0) {
    #pragma unroll
    for (int i = 0; i < 8; ++i) {
      int idx = tid + 256 * i;
      int r = idx >> 5, c = idx & 31;
      int g = j0 + r; g = g < total ? g : total - 1;
      int cp = c ^ (r & 7);
      GLOAD16(zun + (size_t)g * 256 + cp * 8, smem + buf * 32768 + r * 512 + c * 16);
    }
  };

  const int rxor = (lane & 7) << 4;
  const int kcol = (lane >> 4) << 4;
  int cur = 0;
  stage(0, jbeg);
  __syncthreads();                         // drains vmcnt + barrier
  for (int j0 = jbeg; j0 < jend; j0 += 64) {
    if (j0 + 64 < jend) stage(cur ^ 1, j0 + 64);   // async, overlaps compute below
    const int rows = min(64, jend - j0);   // multiple of 16
    const int nsub = rows >> 4;
    const char* base = smem + cur * 32768;
    for (int sub = 0; sub < nsub; ++sub) {
      const char* bb = base + (sub * 16 + (lane & 15)) * 512;
      f32x4 acc[NEG_TILES];
      #pragma unroll
      for (int t = 0; t < NEG_TILES; ++t) acc[t] = (f32x4){0.f, 0.f, 0.f, 0.f};
      __builtin_amdgcn_s_setprio(1);
      #pragma unroll
      for (int ks = 0; ks < 8; ++ks) {
        bf16x8 bfrag = *(const bf16x8*)(bb + ((kcol + ks * 64) ^ rxor));
        #pragma unroll
        for (int t = 0; t < NEG_TILES; ++t)
          acc[t] = __builtin_amdgcn_mfma_f32_16x16x32_bf16(afrag[t][ks], bfrag, acc[t], 0, 0, 0);
      }
      __builtin_amdgcn_s_setprio(0);
      #pragma unroll
      for (int t = 0; t < NEG_TILES; ++t)
        #pragma unroll
        for (int j = 0; j < 4; ++j)
          psum[t][j] += __expf(acc[t][j] * k_exp);
    }
    __syncthreads();                       // drains next-tile GLOADs; protects cur buffer
    cur ^= 1;
  }
  #pragma unroll
  for (int t = 0; t < NEG_TILES; ++t)
    #pragma unroll
    for (int j = 0; j < 4; ++j) {
      float x = psum[t][j];
      x += __shfl_xor(x, 1);
      x += __shfl_xor(x, 2);
      x += __shfl_xor(x, 4);
      x += __shfl_xor(x, 8);
      if (vv[t] && (lane & 15) == 0)
        atomicAdd(&negsim[(itv[t] << 4) + ((lane >> 4) << 2) + j], x);
    }
}

// ---------- loss = mean(-pos1+neg1)/cnt + mean(-pos2+neg2)/cnt ----------
__global__ __launch_bounds__(1024) void k_loss(
    const float* __restrict__ pos1, const float* __restrict__ neg1,
    const float* __restrict__ pos2, const float* __restrict__ neg2,
    const int* __restrict__ cnt, int N, float* __restrict__ out)
{
  __shared__ float lds[1024];
  float s = 0.f;
  for (int i = threadIdx.x; i < N; i += 1024) {
    float denom = fmaxf((float)cnt[i], 1.f);
    s += ((-pos1[i] + neg1[i]) + (-pos2[i] + neg2[i])) / denom;
  }
  lds[threadIdx.x] = s;
  __syncthreads();
  for (int o = 512; o > 0; o >>= 1) {
    if (threadIdx.x < o) lds[threadIdx.x] += lds[threadIdx.x + o];
    __syncthreads();
  }
  if (threadIdx.x == 0) out[0] = lds[0] / (float)N;
}

extern "C" void kernel_launch(void* const* d_in, const int* in_sizes, int n_in,
                              void* d_out, int out_size, void* d_ws, size_t ws_size,
                              hipStream_t stream)
{
  const float* feat  = (const float*)d_in[0];
  const int* src_g   = (const int*)d_in[1];
  const int* dst_g   = (const int*)d_in[2];
  const int* src_s   = (const int*)d_in[3];
  const int* dst_s   = (const int*)d_in[4];
  const float* tau1  = (const float*)d_in[5];
  const float* tau2  = (const float*)d_in[6];
  const float* W1a   = (const float*)d_in[7];
  const float* b1a   = (const float*)d_in[8];
  const float* W1b   = (const float*)d_in[9];
  const float* b1b   = (const float*)d_in[10];
  const float* W1a_t = (const float*)d_in[11];
  const float* b1a_t = (const float*)d_in[12];
  const float* W1b_t = (const float*)d_in[13];
  const float* b1b_t = (const float*)d_in[14];
  const float* W2    = (const float*)d_in[15];
  const float* b2    = (const float*)d_in[16];
  const float* W2_t  = (const float*)d_in[17];
  const float* b2_t  = (const float*)d_in[18];
  const float* Wp    = (const float*)d_in[19];
  const float* bp    = (const float*)d_in[20];

  const int N = in_sizes[0] / 512;
  const int E = in_sizes[1];

  float* out  = (float*)d_out;
  float* v1u1 = out;                               // rows 0..2N-1 (v1 then u1)
  float* v2u2 = out + (size_t)2 * N * 256;         // rows 0..2N-1 (v2 then u2)
  float* loss = out + (size_t)4 * N * 256;

  char* ws = (char*)d_ws;
  size_t off = 0;
  auto alloc = [&](size_t bytes) -> char* {
    char* p = ws + off;
    off += (bytes + 255) & ~(size_t)255;
    return p;
  };
  int* zbase    = (int*)alloc((size_t)11 * N * 4);   // zeroed region
  int* deg_og   = zbase;
  int* deg_ig   = zbase + N;
  int* cnt_s    = zbase + 2 * N;
  int* cursor   = zbase + 3 * N;
  int* cursor_s = zbase + 4 * N;
  float* pos1   = (float*)(zbase + 5 * N);
  float* neg1   = (float*)(zbase + 6 * N);
  float* pos2   = (float*)(zbase + 7 * N);
  float* neg2   = (float*)(zbase + 8 * N);
  float* negs1  = (float*)(zbase + 9 * N);
  float* negs2  = (float*)(zbase + 10 * N);
  int* offs    = (int*)alloc((size_t)(N + 1) * 4);
  int* offs_s  = (int*)alloc((size_t)(N + 1) * 4);
  int* csr_src = (int*)alloc((size_t)E * 4);
  int* csr_es  = (int*)alloc((size_t)E * 4);
  float* ns    = (float*)alloc((size_t)N * 4);
  float* nd    = (float*)alloc((size_t)N * 4);
  unsigned short* featb   = (unsigned short*)alloc((size_t)N * 512 * 2);
  unsigned short* wcatL1  = (unsigned short*)alloc((size_t)1024 * 512 * 2);
  unsigned short* wcat2   = (unsigned short*)alloc((size_t)512 * 512 * 2);
  unsigned short* wcatLin = (unsigned short*)alloc((size_t)512 * 512 * 2);
  unsigned short* wtp     = (unsigned short*)alloc((size_t)256 * 256 * 2);
  float* bcatL1  = (float*)alloc(1024 * 4);
  float* bcatGcn = (float*)alloc(512 * 4);
  float* bcatLin = (float*)alloc(512 * 4);
  char* BUF_H = alloc((size_t)N * 2048);  // hcat [N][1024] bf16 -> q_raw [2N][256] f32
  char* BUF_A = alloc((size_t)N * 1024);  // Xaggb -> g2cat -> qb
  char* BUF_B = alloc((size_t)N * 1024);  // zun1 [2N][256] bf16
  char* BUF_C = alloc((size_t)N * 1024);  // zun2
  char* BUF_E = alloc((size_t)N * 1024);  // v1b || v2b
  if (off > ws_size) return;  // workspace too small -> visible failure

  unsigned short* Xaggb = (unsigned short*)BUF_A;
  unsigned short* hcat  = (unsigned short*)BUF_H;
  unsigned short* g2cat = (unsigned short*)BUF_A;            // Xaggb dead after gemmL1
  unsigned short* v1b   = (unsigned short*)BUF_E;
  float*          q_raw = (float*)BUF_H;                     // hcat dead after gemmL2
  unsigned short* qb    = (unsigned short*)BUF_A;            // g2cat dead after aggdual
  unsigned short* zun1  = (unsigned short*)BUF_B;
  unsigned short* zun2  = (unsigned short*)BUF_C;

  const int eb = (E + 255) / 256;
  const int gmx = (N + 127) / 128;
  const int gqx = (2 * N + 127) / 128;
  const int ntiles = N / 16;
  const int nquads = (ntiles + NEG_TILES - 1) / NEG_TILES;
  const dim3 neggrid((nquads + 3) / 4, NEG_JSPLIT, 2);
  const dim3 edgegrid((N + 3) / 4, 2);
  const dim3 nrmgrid((2 * N + 3) / 4, 3);
  const int scanblocks = 2 + (N + 1023) / 1024;

  hipMemsetAsync(zbase, 0, (size_t)11 * N * 4, stream);
  k_count<<<eb, 256, 0, stream>>>(src_g, dst_g, dst_s, deg_og, deg_ig, cnt_s, E);
  k_scan<<<scanblocks, 1024, 0, stream>>>(deg_ig, offs, cnt_s, offs_s,
                                          deg_og, deg_ig, ns, nd, N);
  k_fill<<<dim3(eb, 2), 256, 0, stream>>>(src_g, dst_g, offs, cursor, csr_src,
                                          src_s, dst_s, offs_s, cursor_s, csr_es, E);

  PrepArgs pa;
  pa.feat = feat; pa.W1a = W1a; pa.W1at = W1a_t; pa.W1b = W1b; pa.W1bt = W1b_t;
  pa.W2 = W2; pa.W2t = W2_t; pa.Wp = Wp;
  pa.b1a = b1a; pa.b1at = b1a_t; pa.b1b = b1b; pa.b1bt = b1b_t; pa.b2 = b2; pa.b2t = b2_t;
  pa.featb = featb; pa.wcatL1 = wcatL1; pa.wcat2 = wcat2; pa.wcatLin = wcatLin; pa.wtp = wtp;
  pa.bcatL1 = bcatL1; pa.bcatGcn = bcatGcn; pa.bcatLin = bcatLin;
  pa.NF = N * 512;
  const int ptotal = pa.NF + 1024 * 512 + 512 * 512 + 512 * 512 + 256 * 256 + 1024 + 512 + 512;
  k_prep<<<(ptotal + 255) / 256, 256, 0, stream>>>(pa);

  // Shared layer-1 aggregate (agg(X@W) == agg(X)@W), then concat GEMMs
  k_agg<<<N / 4, 256, 0, stream>>>(featb, offs, csr_src, ns, nd, nullptr, nullptr, Xaggb, 0, 0);
  k_mgemm<<<dim3(gmx, 16), 256, 0, stream>>>(Xaggb, 512, wcatL1, bcatL1, nullptr, hcat,
                                             N, 512, 1024, 1, 0, 0);
  k_mgemm<<<dim3(gmx, 8), 256, 0, stream>>>(hcat, 1024, wcat2, nullptr, nullptr, g2cat,
                                            N, 512, 512, 0, 256, 0);
  k_agg<<<N / 4, 256, 0, stream>>>(g2cat, offs, csr_src, ns, nd, bcatGcn, v1u1, v1b, 0, N);
  k_mgemm<<<dim3(gmx, 8), 256, 0, stream>>>(featb, 512, wcatLin, bcatLin, v2u2,
                                            (unsigned short*)BUF_E + (size_t)N * 256,
                                            N, 512, 512, 0, 0, N);
  // projector for both branches in one GEMM (A = v1b||v2b, 2N rows)
  k_mgemm<<<dim3(gqx, 4), 256, 0, stream>>>((unsigned short*)BUF_E, 256, wtp, bp, q_raw, nullptr,
                                            2 * N, 256, 256, 0, 0, 0);

  // normalizations (3 streams x 2N rows, one dispatch)
  k_normrows3<<<nrmgrid, 256, 0, stream>>>(v1u1, zun1, v2u2, zun2, q_raw, qb, 2 * N);

  // scores (both branches per dispatch)
  k_negsim<<<neggrid, 256, 0, stream>>>(zun1, zun2, tau1, tau2, negs1, negs2, N);
  k_edge<<<edgegrid, 256, 0, stream>>>(zun1, zun2, qb, offs_s, csr_es, tau1, tau2,
                                       negs1, negs2, pos1, neg1, pos2, neg2, N);
  k_loss<<<1, 1024, 0, stream>>>(pos1, neg1, pos2, neg2, cnt_s, N, loss);
}